// Round 2
// baseline (235.750 us; speedup 1.0000x reference)
//
#include <hip/hip_runtime.h>

// Causal single-head attention, B=4 S=4096 Dm=256 Dqk=64, fp32 in/out.
// R10 = R9 resubmission (previous bench died to container infra failure, no
// counters; kernel re-audited: barrier counts match across the wave-uniform
// branch, (j1-j0)+2 on both sides; all ws indices bounds-checked clean).
// R9: wave specialization in attn. R8's 8 symmetric waves convoy (all waves
// S^T/exp together, then all PV together: MfmaUtil 15 + VALUBusy 25, per-iter
// 10.6k cyc vs 3.4k pipe floor). Split: waves 0-3 = producers (S^T for k-sub w
// x all 4 q-subs, exp/mask/den/pack into double-buffered Pb), waves 4-7 =
// consumers (PV for 2 e-tiles each, V frags refilled use-then-reload in regs).
// Each SIMD now runs 1 producer (VALU/trans) + 1 consumer (MFMA/LDS) -> cross-
// pipe overlap instead of phase convoy. One barrier/iter, arrival-order paired
// across the wave-uniform branch; separate loops keep reg sets disjoint
// (producer ~150, consumer ~228 < 256 at 2 waves/SIMD). Math bitwise = R8.
// Task map / proj / combine / ws layout unchanged from R8 (19.5MB).

#define BATCH 4
#define SEQ   4096
#define DM    256
#define DQK   64

typedef __bf16 bf16x8 __attribute__((ext_vector_type(8)));
typedef float  f32x16 __attribute__((ext_vector_type(16)));

__device__ __forceinline__ unsigned int rnd16(unsigned int u) {
    return u + 0x7fffu + ((u >> 16) & 1u);          // RNE to bf16 in high half
}
__device__ __forceinline__ unsigned short f2bf(float f) {
    return (unsigned short)(rnd16(__builtin_bit_cast(unsigned int, f)) >> 16);
}
__device__ __forceinline__ unsigned int pk2bf(float lo, float hi) {
    unsigned int a = rnd16(__builtin_bit_cast(unsigned int, lo));
    unsigned int b = rnd16(__builtin_bit_cast(unsigned int, hi));
    return (a >> 16) | (b & 0xffff0000u);           // elem0 low, elem1 high
}
__device__ __forceinline__ bf16x8 u4bf(uint4 u) { return __builtin_bit_cast(bf16x8, u); }

// Repack a 32x32x16 MFMA accumulator D[m][n] (C-layout: col(n)=lane&31,
// row(m)=(r&3)+8(r>>2)+4(lane>>5)) into two 1KB fragment chunks where the
// fragment k-dim = m and lane-dim = n, then store. (Verified R2/R3.)
__device__ __forceinline__ void repack_store(const f32x16& acc, int q2, int l,
                                             uint4* __restrict__ out, size_t tile_ofs_u4) {
    unsigned int d0[4], d1[4], p0[4], p1[4];
#pragma unroll
    for (int h = 0; h < 4; ++h) {
        d0[h] = pk2bf(acc[4*h + 0], acc[4*h + 1]);
        d1[h] = pk2bf(acc[4*h + 2], acc[4*h + 3]);
        p0[h] = __shfl_xor((int)d0[h], 32);
        p1[h] = __shfl_xor((int)d1[h], 32);
    }
#pragma unroll
    for (int kc = 0; kc < 2; ++kc) {
        int h = 2*kc + q2;
        uint4 v = (q2 == 0) ? make_uint4(d0[h], d1[h], p0[h], p1[h])
                            : make_uint4(p0[h], p1[h], d0[h], d1[h]);
        out[tile_ofs_u4 + (size_t)kc * 64 + l] = v;
    }
}

// R3 task map: nc=1 (T<12), 2 (12..23), 3 (24..31).
// Op slots (chunks cc>=1): T 12..23 -> 1 slot, 24..31 -> 2. 28/batch.
__device__ __forceinline__ int obase(int T) {
    return (T < 24) ? (T - 12) : 12 + (T - 24) * 2;
}
// Dp slots (all chunks of split tasks): 48/batch.
__device__ __forceinline__ int dbase(int T) {
    return (T < 24) ? (T - 12) * 2 : 24 + (T - 24) * 3;
}

// ---------------------------------------------------------------------------
// Fused projection. grid (64 s-tiles, 4 batch, 4): z=0 Q, z=1 K, z=2 V(ec 0,1),
// z=3 V(ec 2,3). Coalesced fp32 staging -> bf16 LDS -> 32x32x16 MFMA ->
// frag-packed ws.  (Unchanged from R8.)
// ---------------------------------------------------------------------------
__global__ __launch_bounds__(256) void proj(const float* __restrict__ Xq,
                                            const float* __restrict__ Xk,
                                            const float* __restrict__ Xv,
                                            const float* __restrict__ Wq,
                                            const float* __restrict__ Wk,
                                            const float* __restrict__ Wv,
                                            uint4* __restrict__ qf,
                                            uint4* __restrict__ kf,
                                            uint4* __restrict__ vf) {
    __shared__ unsigned short Xs[64][264];
    __shared__ unsigned short Ws[64][264];

    const int z = blockIdx.z;
    const int bx = blockIdx.x, b = blockIdx.y;
    const float* X = (z == 0) ? Xq : (z == 1) ? Xk : Xv;
    const float* W = (z == 0) ? Wq : (z == 1) ? Wk : Wv;
    const int s0 = bx * 64;
    const int tid = threadIdx.x, w = tid >> 6, l = tid & 63, ln = l & 31, q2 = l >> 5;

#pragma unroll
    for (int i = 0; i < 16; ++i) {
        int f = i * 256 + tid;
        int r = f >> 6, c4 = f & 63;
        float4 xv = *(const float4*)&X[((size_t)b * SEQ + s0 + r) * DM + c4 * 4];
        ushort4 h; h.x = f2bf(xv.x); h.y = f2bf(xv.y); h.z = f2bf(xv.z); h.w = f2bf(xv.w);
        *(ushort4*)&Xs[r][c4 * 4] = h;
    }

    if (z < 2) {
        // ---- Q/K: D[m=e (64)][n=s (64)] ----
#pragma unroll
        for (int i = 0; i < 16; ++i) {
            int f = i * 256 + tid;
            int r = f >> 6, c4 = f & 63;
            float4 wv = *(const float4*)&W[(size_t)r * DM + c4 * 4];
            ushort4 h; h.x = f2bf(wv.x); h.y = f2bf(wv.y); h.z = f2bf(wv.z); h.w = f2bf(wv.w);
            *(ushort4*)&Ws[r][c4 * 4] = h;
        }
        __syncthreads();
        const int msub = w >> 1, nsub = w & 1;
        f32x16 a0 = {}, a1 = {};
#pragma unroll
        for (int c = 0; c < 16; c += 2) {
            bf16x8 af0 = u4bf(*(const uint4*)&Ws[msub*32 + ln][c*16 + q2*8]);
            bf16x8 bf0 = u4bf(*(const uint4*)&Xs[nsub*32 + ln][c*16 + q2*8]);
            a0 = __builtin_amdgcn_mfma_f32_32x32x16_bf16(af0, bf0, a0, 0, 0, 0);
            bf16x8 af1 = u4bf(*(const uint4*)&Ws[msub*32 + ln][(c+1)*16 + q2*8]);
            bf16x8 bf1 = u4bf(*(const uint4*)&Xs[nsub*32 + ln][(c+1)*16 + q2*8]);
            a1 = __builtin_amdgcn_mfma_f32_32x32x16_bf16(af1, bf1, a1, 0, 0, 0);
        }
        f32x16 acc = a0 + a1;
        size_t base = (((size_t)(b*128 + bx*2 + nsub)) * 4 + 2*msub) * 64;
        repack_store(acc, q2, l, (z == 0) ? qf : kf, base);
    } else {
        // ---- V: D[m=s (64)][n=e], e-chunks (z-2)*2 .. +1 ----
        const int msub = w & 1, nsub = w >> 1;
        for (int ecl = 0; ecl < 2; ++ecl) {
            const int ec = (z - 2) * 2 + ecl;
            __syncthreads();
#pragma unroll
            for (int i = 0; i < 16; ++i) {
                int f = i * 256 + tid;
                int r = f >> 6, c4 = f & 63;
                float4 wv = *(const float4*)&W[(size_t)(ec*64 + r) * DM + c4 * 4];
                ushort4 h; h.x = f2bf(wv.x); h.y = f2bf(wv.y); h.z = f2bf(wv.z); h.w = f2bf(wv.w);
                *(ushort4*)&Ws[r][c4 * 4] = h;
            }
            __syncthreads();
            f32x16 a0 = {}, a1 = {};
#pragma unroll
            for (int c = 0; c < 16; c += 2) {
                bf16x8 af0 = u4bf(*(const uint4*)&Xs[msub*32 + ln][c*16 + q2*8]);
                bf16x8 bf0 = u4bf(*(const uint4*)&Ws[nsub*32 + ln][c*16 + q2*8]);
                a0 = __builtin_amdgcn_mfma_f32_32x32x16_bf16(af0, bf0, a0, 0, 0, 0);
                bf16x8 af1 = u4bf(*(const uint4*)&Xs[msub*32 + ln][(c+1)*16 + q2*8]);
                bf16x8 bf1 = u4bf(*(const uint4*)&Ws[nsub*32 + ln][(c+1)*16 + q2*8]);
                a1 = __builtin_amdgcn_mfma_f32_32x32x16_bf16(af1, bf1, a1, 0, 0, 0);
            }
            f32x16 acc = a0 + a1;
            int et = ec*2 + nsub;
            size_t base = (((size_t)(b*8 + et)) * 256 + (size_t)bx*4 + msub*2) * 64;
            repack_store(acc, q2, l, vf, base);
        }
    }
}

// ---------------------------------------------------------------------------
// Attention. 240 blocks x 512 thr, 1 block/CU. Task = (b, T, chunk cc of nc).
// slot = bid&7 -> b = slot>>1, parity = slot&1 (XCD batch-pinning, L2-proven).
// R9 roles: waves 0-3 producers (ks = w): S^T(jt) over 4 q-subs, exp/pack into
// Pb[jt&1], prefetch kaf(jt+1). Waves 4-7 consumers (e-tiles 2(w-4),2(w-4)+1):
// PV(jt-1) from Pb[(jt-1)&1] with per-kc V-frag refill to tile jt. One barrier
// per region; Pb double-buffer gives producer-write/consumer-read separation.
// Barrier pairing: both sides execute (j1-j0)+2 s_barriers exactly.
// ---------------------------------------------------------------------------
__global__ __launch_bounds__(512, 2) void attn(const uint4* __restrict__ qf,
                                               const uint4* __restrict__ kf,
                                               const uint4* __restrict__ vf,
                                               float* __restrict__ out,
                                               unsigned short* __restrict__ Op,
                                               float* __restrict__ Dp) {
    __shared__ uint4 Pb[2][4][8][64];        // 64KB, double-buffered P
    __shared__ float denp[4][4][64];         // [producer ks][qsub][lane]
    __shared__ float dfin[128];

    const int bid = blockIdx.x;
    const int slot = bid & 7, u = bid >> 3;
    const int b = slot >> 1;
    const int task = u * 2 + (slot & 1);     // [0,60)
    int T, cc, nc;
    if (task < 12)      { T = task;                cc = 0;               nc = 1; }
    else if (task < 36) { int q = task - 12; T = 12 + (q >> 1); cc = q & 1;       nc = 2; }
    else                { int q = task - 36; T = 24 + q / 3;    cc = q - 3*(q/3); nc = 3; }
    const int n = T + 1;
    const int j0 = cc * n / nc, j1 = (cc + 1) * n / nc;

    const int tid = threadIdx.x, w = tid >> 6, l = tid & 63, ln = l & 31, q2 = l >> 5;
    const float cfac = 0.18033688011112042f; // log2(e)/sqrt(64)

    if (w < 4) {
        // ================= producer: S^T + exp/mask/den/pack =================
        const int ks = w;
        bf16x8 qv[4][4];
#pragma unroll
        for (int qs = 0; qs < 4; ++qs)
#pragma unroll
            for (int c = 0; c < 4; ++c)
                qv[qs][c] = u4bf(qf[(((size_t)b*128 + T*4 + qs) * 4 + c) * 64 + l]);

        uint4 kaf[4];
#pragma unroll
        for (int c = 0; c < 4; ++c)
            kaf[c] = kf[(((size_t)b*128 + j0*4 + ks) * 4 + c) * 64 + l];

        float den[4] = {0.f, 0.f, 0.f, 0.f};

        for (int jt = j0; jt < j1; ++jt) {
            const int buf = jt & 1;
            const bool diag = (jt == T);
            // q-subs in 2 groups of 2: caps live S^T accumulators at 32 regs
#pragma unroll
            for (int g2 = 0; g2 < 2; ++g2) {
                f32x16 s0 = {}, s1 = {};
#pragma unroll
                for (int c = 0; c < 4; ++c) {
                    bf16x8 ka = u4bf(kaf[c]);
                    s0 = __builtin_amdgcn_mfma_f32_32x32x16_bf16(ka, qv[2*g2+0][c], s0, 0, 0, 0);
                    s1 = __builtin_amdgcn_mfma_f32_32x32x16_bf16(ka, qv[2*g2+1][c], s1, 0, 0, 0);
                }
#pragma unroll
                for (int g = 0; g < 2; ++g) {
                    const f32x16 s = g ? s1 : s0;
                    const int qsub = 2*g2 + g;
                    float pv[16], pd = 0.f;
#pragma unroll
                    for (int r = 0; r < 16; ++r) {
                        float e = __builtin_exp2f(s[r] * cfac);
                        if (diag) {
                            int klocal = 4*q2 + (r & 3) + 8*(r >> 2);
                            if (ks*32 + klocal > qsub*32 + ln) e = 0.f;
                        }
                        pv[r] = e; pd += e;
                    }
                    den[qsub] += pd;
#pragma unroll
                    for (int quad = 0; quad < 4; ++quad) {
                        unsigned int lo = pk2bf(pv[4*quad + 0], pv[4*quad + 1]);
                        unsigned int hi = pk2bf(pv[4*quad + 2], pv[4*quad + 3]);
                        int kcg = ks*2 + (quad >> 1);
                        int h   = quad & 1;
                        char* dst = (char*)&Pb[buf][qsub][kcg][h*32 + ln] + q2*8;
                        *(uint2*)dst = make_uint2(lo, hi);
                    }
                }
            }
            // prefetch next K-frags; latency covered by barrier wait (consumers
            // are the late arrivals)
            if (jt + 1 < j1) {
#pragma unroll
                for (int c = 0; c < 4; ++c)
                    kaf[c] = kf[(((size_t)b*128 + (jt+1)*4 + ks) * 4 + c) * 64 + l];
            }
            __syncthreads();
        }
        // ---- den reduction (producers idle while consumers do final PV) ----
#pragma unroll
        for (int qs = 0; qs < 4; ++qs) denp[ks][qs][l] = den[qs];
        __syncthreads();                          // A
        if (tid < 128) {
            int qsub = tid >> 5, qln = tid & 31;
            float sden = 0.f;
#pragma unroll
            for (int p = 0; p < 4; ++p)
#pragma unroll
                for (int hh = 0; hh < 2; ++hh)
                    sden += denp[p][qsub][hh*32 + qln];
            dfin[tid] = (nc == 1) ? 1.0f / sden : sden;
        }
        __syncthreads();                          // B
        if (nc > 1 && tid < 128)
            Dp[((size_t)b*48 + dbase(T) + cc) * 128 + tid] = dfin[tid];
    } else {
        // ================= consumer: PV with in-reg V refill =================
        const int cw = w - 4;                    // e-tiles 2cw, 2cw+1
        uint4 vbs[2][8];
        f32x16 oa[2][4] = {};
        for (int jt = j0; jt < j1; ++jt) {
            if (jt == j0) {
                // pipeline fill: plain-load V(j0); latency covered by the
                // producers' region-j0 work before the barrier
#pragma unroll
                for (int e = 0; e < 2; ++e)
#pragma unroll
                    for (int kc = 0; kc < 8; ++kc)
                        vbs[e][kc] = vf[(((size_t)b*8 + (2*cw+e)) * 256 + (size_t)j0*8 + kc) * 64 + l];
            } else {
                const int buf = (jt - 1) & 1;    // PV tile jt-1
#pragma unroll
                for (int kc = 0; kc < 8; ++kc) {
                    bf16x8 pa[4];
#pragma unroll
                    for (int qs = 0; qs < 4; ++qs)
                        pa[qs] = u4bf(Pb[buf][qs][kc][l]);
#pragma unroll
                    for (int e = 0; e < 2; ++e) {
                        bf16x8 vb = u4bf(vbs[e][kc]);
#pragma unroll
                        for (int qs = 0; qs < 4; ++qs)
                            oa[e][qs] = __builtin_amdgcn_mfma_f32_32x32x16_bf16(pa[qs], vb, oa[e][qs], 0, 0, 0);
                    }
                    // use-then-refill: load V(jt)[kc]; remaining MFMA groups
                    // cover the L2 latency
#pragma unroll
                    for (int e = 0; e < 2; ++e)
                        vbs[e][kc] = vf[(((size_t)b*8 + (2*cw+e)) * 256 + (size_t)jt*8 + kc) * 64 + l];
                }
            }
            __syncthreads();
        }
        __syncthreads();                          // A (producers write denp)
        {   // final PV(j1-1); overlaps producers' den reduce
            const int buf = (j1 - 1) & 1;
#pragma unroll
            for (int kc = 0; kc < 8; ++kc) {
                bf16x8 pa[4];
#pragma unroll
                for (int qs = 0; qs < 4; ++qs)
                    pa[qs] = u4bf(Pb[buf][qs][kc][l]);
#pragma unroll
                for (int e = 0; e < 2; ++e) {
                    bf16x8 vb = u4bf(vbs[e][kc]);
#pragma unroll
                    for (int qs = 0; qs < 4; ++qs)
                        oa[e][qs] = __builtin_amdgcn_mfma_f32_32x32x16_bf16(pa[qs], vb, oa[e][qs], 0, 0, 0);
                }
            }
        }
        __syncthreads();                          // B (dfin ready)
        if (nc == 1) {
#pragma unroll
            for (int e = 0; e < 2; ++e) {
                const int et = 2*cw + e;
#pragma unroll
                for (int qs = 0; qs < 4; ++qs)
#pragma unroll
                    for (int r = 0; r < 16; ++r) {
                        int qrow = qs*32 + (r & 3) + 8*(r >> 2) + 4*q2;
                        out[((size_t)b*SEQ + T*128 + qrow) * DM + et*32 + ln] = oa[e][qs][r] * dfin[qrow];
                    }
            }
        } else if (cc == 0) {
            // chunk 0: unnormalized fp32 straight into out (combine divides)
#pragma unroll
            for (int e = 0; e < 2; ++e) {
                const int et = 2*cw + e;
#pragma unroll
                for (int qs = 0; qs < 4; ++qs)
#pragma unroll
                    for (int r = 0; r < 16; ++r) {
                        int qrow = qs*32 + (r & 3) + 8*(r >> 2) + 4*q2;
                        out[((size_t)b*SEQ + T*128 + qrow) * DM + et*32 + ln] = oa[e][qs][r];
                    }
            }
        } else {
            size_t pidx = (size_t)b*28 + obase(T) + (cc - 1);
#pragma unroll
            for (int e = 0; e < 2; ++e) {
                const int et = 2*cw + e;
#pragma unroll
                for (int qs = 0; qs < 4; ++qs)
#pragma unroll
                    for (int r = 0; r < 16; ++r) {
                        int qrow = qs*32 + (r & 3) + 8*(r >> 2) + 4*q2;
                        Op[(pidx*128 + qrow) * DM + et*32 + ln] = f2bf(oa[e][qs][r]);
                    }
            }
        }
    }
}

// ---------------------------------------------------------------------------
// Combine partials for T in [12,32). grid (20, 4, 4 q-quarters) x 256 thr.
// out holds chunk-0's unnormalized fp32; add bf16 chunks >=1, divide by den.
// (Unchanged from R8.)
// ---------------------------------------------------------------------------
__global__ __launch_bounds__(256) void combine(const unsigned short* __restrict__ Op,
                                               const float* __restrict__ Dp,
                                               float* __restrict__ out) {
    const int T = 12 + blockIdx.x, b = blockIdx.y, qq = blockIdx.z;
    const int nc = (T < 24) ? 2 : 3;
    const int t = threadIdx.x;
    const size_t db = (size_t)b*48 + dbase(T);
    const size_t pb = (size_t)b*28 + obase(T);
#pragma unroll 4
    for (int r = 0; r < 32; ++r) {
        int q = qq*32 + r;
        size_t oofs = ((size_t)b*SEQ + T*128 + q) * DM + t;
        float sum = out[oofs];
        float dsum = 0.f;
        for (int c = 0; c < nc; ++c) dsum += Dp[(db + c)*128 + q];
        for (int c = 1; c < nc; ++c) {
            unsigned int uv = Op[((pb + c - 1)*128 + q) * DM + t];
            sum += __builtin_bit_cast(float, uv << 16);
        }
        out[oofs] = sum / dsum;
    }
}

// ---------------------------------------------------------------------------
extern "C" void kernel_launch(void* const* d_in, const int* in_sizes, int n_in,
                              void* d_out, int out_size, void* d_ws, size_t ws_size,
                              hipStream_t stream) {
    const float* enc_q = (const float*)d_in[0];
    const float* enc_k = (const float*)d_in[1];
    const float* enc_v = (const float*)d_in[2];
    // d_in[3] = mask (deterministic causal triu) — not needed
    const float* Wq = (const float*)d_in[4];
    const float* Wk = (const float*)d_in[5];
    const float* Wv = (const float*)d_in[6];
    float* out = (float*)d_out;

    uint4* qf = (uint4*)d_ws;                              // 2MB
    uint4* kf = qf + 131072;                               // 2MB
    uint4* vf = kf + 131072;                               // 8MB
    unsigned short* Op = (unsigned short*)(vf + 524288);   // [4][28][128][256] bf16, 7.34MB
    float* Dp = (float*)(Op + (size_t)4*28*128*256);       // [4][48][128] f32, 98KB

    proj<<<dim3(64, 4, 4), 256, 0, stream>>>(enc_q, enc_k, enc_v, Wq, Wk, Wv, qf, kf, vf);
    attn<<<240, 512, 0, stream>>>(qf, kf, vf, out, Op, Dp);
    combine<<<dim3(20, 4, 4), 256, 0, stream>>>(Op, Dp, out);
}

// Round 3
// 208.749 us; speedup vs baseline: 1.1293x; 1.1293x over previous
//
#include <hip/hip_runtime.h>

// Causal single-head attention, B=4 S=4096 Dm=256 Dqk=64, fp32 in/out.
// R11: back to R8's proven symmetric-wave structure (R9/R10 specialization
// REGRESSED: consumer branch spilled — FETCH +3.4MB / WRITE +6MB of scratch —
// and the barrier convoyed on the 64-MFMA consumer side). R8 diagnosis stands:
// latency/convoy-bound (no pipe >40%), 1 block/CU, one barrier group, 2
// waves/SIMD. Fix = TLP: split every task along Q into halves (64 rows). Per-
// wave state halves (oa[2]=32 acc, qv[4]=16, one S^T accum), Pb halves to
// 32KB -> LDS/block ~34.5KB, regs ~150 -> TWO blocks/CU resident (grid 480,
// all resident, 4 waves/SIMD in 2 INDEPENDENT barrier groups; block A's
// barrier wait is covered by block B's issue). Wave w: S^T role (ks=w&3,
// qg=w>>2 -> 1 q-sub, 4 MFMA, 16 exp), PV role (e-tile w, oa[2 qsub]).
// ws layout / Op / Dp / combine / proj identical to R8 (q-halves write
// disjoint 64-row halves of the same slots). Per-row den sum order unchanged
// -> bitwise-identical numerics. XCD pinning: slot=bid&7 -> (b,qh): per-XCD
// working set K+V+Q/2 ~2.75MB < 4MB L2.
// ws: qf 2MB + kf 2MB + vf 8MB + Op 7.34MB + Dp 98KB = 19.5MB.

#define BATCH 4
#define SEQ   4096
#define DM    256
#define DQK   64

typedef __bf16 bf16x8 __attribute__((ext_vector_type(8)));
typedef float  f32x16 __attribute__((ext_vector_type(16)));

__device__ __forceinline__ unsigned int rnd16(unsigned int u) {
    return u + 0x7fffu + ((u >> 16) & 1u);          // RNE to bf16 in high half
}
__device__ __forceinline__ unsigned short f2bf(float f) {
    return (unsigned short)(rnd16(__builtin_bit_cast(unsigned int, f)) >> 16);
}
__device__ __forceinline__ unsigned int pk2bf(float lo, float hi) {
    unsigned int a = rnd16(__builtin_bit_cast(unsigned int, lo));
    unsigned int b = rnd16(__builtin_bit_cast(unsigned int, hi));
    return (a >> 16) | (b & 0xffff0000u);           // elem0 low, elem1 high
}
__device__ __forceinline__ bf16x8 u4bf(uint4 u) { return __builtin_bit_cast(bf16x8, u); }

// Repack a 32x32x16 MFMA accumulator D[m][n] (C-layout: col(n)=lane&31,
// row(m)=(r&3)+8(r>>2)+4(lane>>5)) into two 1KB fragment chunks where the
// fragment k-dim = m and lane-dim = n, then store. (Verified R2/R3.)
__device__ __forceinline__ void repack_store(const f32x16& acc, int q2, int l,
                                             uint4* __restrict__ out, size_t tile_ofs_u4) {
    unsigned int d0[4], d1[4], p0[4], p1[4];
#pragma unroll
    for (int h = 0; h < 4; ++h) {
        d0[h] = pk2bf(acc[4*h + 0], acc[4*h + 1]);
        d1[h] = pk2bf(acc[4*h + 2], acc[4*h + 3]);
        p0[h] = __shfl_xor((int)d0[h], 32);
        p1[h] = __shfl_xor((int)d1[h], 32);
    }
#pragma unroll
    for (int kc = 0; kc < 2; ++kc) {
        int h = 2*kc + q2;
        uint4 v = (q2 == 0) ? make_uint4(d0[h], d1[h], p0[h], p1[h])
                            : make_uint4(p0[h], p1[h], d0[h], d1[h]);
        out[tile_ofs_u4 + (size_t)kc * 64 + l] = v;
    }
}

// R3 task map: nc=1 (T<12), 2 (12..23), 3 (24..31).
// Op slots (chunks cc>=1): T 12..23 -> 1 slot, 24..31 -> 2. 28/batch.
__device__ __forceinline__ int obase(int T) {
    return (T < 24) ? (T - 12) : 12 + (T - 24) * 2;
}
// Dp slots (all chunks of split tasks): 48/batch.
__device__ __forceinline__ int dbase(int T) {
    return (T < 24) ? (T - 12) * 2 : 24 + (T - 24) * 3;
}

// ---------------------------------------------------------------------------
// Fused projection. grid (64 s-tiles, 4 batch, 4): z=0 Q, z=1 K, z=2 V(ec 0,1),
// z=3 V(ec 2,3). Coalesced fp32 staging -> bf16 LDS -> 32x32x16 MFMA ->
// frag-packed ws.  (Unchanged from R8.)
// ---------------------------------------------------------------------------
__global__ __launch_bounds__(256) void proj(const float* __restrict__ Xq,
                                            const float* __restrict__ Xk,
                                            const float* __restrict__ Xv,
                                            const float* __restrict__ Wq,
                                            const float* __restrict__ Wk,
                                            const float* __restrict__ Wv,
                                            uint4* __restrict__ qf,
                                            uint4* __restrict__ kf,
                                            uint4* __restrict__ vf) {
    __shared__ unsigned short Xs[64][264];
    __shared__ unsigned short Ws[64][264];

    const int z = blockIdx.z;
    const int bx = blockIdx.x, b = blockIdx.y;
    const float* X = (z == 0) ? Xq : (z == 1) ? Xk : Xv;
    const float* W = (z == 0) ? Wq : (z == 1) ? Wk : Wv;
    const int s0 = bx * 64;
    const int tid = threadIdx.x, w = tid >> 6, l = tid & 63, ln = l & 31, q2 = l >> 5;

#pragma unroll
    for (int i = 0; i < 16; ++i) {
        int f = i * 256 + tid;
        int r = f >> 6, c4 = f & 63;
        float4 xv = *(const float4*)&X[((size_t)b * SEQ + s0 + r) * DM + c4 * 4];
        ushort4 h; h.x = f2bf(xv.x); h.y = f2bf(xv.y); h.z = f2bf(xv.z); h.w = f2bf(xv.w);
        *(ushort4*)&Xs[r][c4 * 4] = h;
    }

    if (z < 2) {
        // ---- Q/K: D[m=e (64)][n=s (64)] ----
#pragma unroll
        for (int i = 0; i < 16; ++i) {
            int f = i * 256 + tid;
            int r = f >> 6, c4 = f & 63;
            float4 wv = *(const float4*)&W[(size_t)r * DM + c4 * 4];
            ushort4 h; h.x = f2bf(wv.x); h.y = f2bf(wv.y); h.z = f2bf(wv.z); h.w = f2bf(wv.w);
            *(ushort4*)&Ws[r][c4 * 4] = h;
        }
        __syncthreads();
        const int msub = w >> 1, nsub = w & 1;
        f32x16 a0 = {}, a1 = {};
#pragma unroll
        for (int c = 0; c < 16; c += 2) {
            bf16x8 af0 = u4bf(*(const uint4*)&Ws[msub*32 + ln][c*16 + q2*8]);
            bf16x8 bf0 = u4bf(*(const uint4*)&Xs[nsub*32 + ln][c*16 + q2*8]);
            a0 = __builtin_amdgcn_mfma_f32_32x32x16_bf16(af0, bf0, a0, 0, 0, 0);
            bf16x8 af1 = u4bf(*(const uint4*)&Ws[msub*32 + ln][(c+1)*16 + q2*8]);
            bf16x8 bf1 = u4bf(*(const uint4*)&Xs[nsub*32 + ln][(c+1)*16 + q2*8]);
            a1 = __builtin_amdgcn_mfma_f32_32x32x16_bf16(af1, bf1, a1, 0, 0, 0);
        }
        f32x16 acc = a0 + a1;
        size_t base = (((size_t)(b*128 + bx*2 + nsub)) * 4 + 2*msub) * 64;
        repack_store(acc, q2, l, (z == 0) ? qf : kf, base);
    } else {
        // ---- V: D[m=s (64)][n=e], e-chunks (z-2)*2 .. +1 ----
        const int msub = w & 1, nsub = w >> 1;
        for (int ecl = 0; ecl < 2; ++ecl) {
            const int ec = (z - 2) * 2 + ecl;
            __syncthreads();
#pragma unroll
            for (int i = 0; i < 16; ++i) {
                int f = i * 256 + tid;
                int r = f >> 6, c4 = f & 63;
                float4 wv = *(const float4*)&W[(size_t)(ec*64 + r) * DM + c4 * 4];
                ushort4 h; h.x = f2bf(wv.x); h.y = f2bf(wv.y); h.z = f2bf(wv.z); h.w = f2bf(wv.w);
                *(ushort4*)&Ws[r][c4 * 4] = h;
            }
            __syncthreads();
            f32x16 a0 = {}, a1 = {};
#pragma unroll
            for (int c = 0; c < 16; c += 2) {
                bf16x8 af0 = u4bf(*(const uint4*)&Xs[msub*32 + ln][c*16 + q2*8]);
                bf16x8 bf0 = u4bf(*(const uint4*)&Ws[nsub*32 + ln][c*16 + q2*8]);
                a0 = __builtin_amdgcn_mfma_f32_32x32x16_bf16(af0, bf0, a0, 0, 0, 0);
                bf16x8 af1 = u4bf(*(const uint4*)&Xs[msub*32 + ln][(c+1)*16 + q2*8]);
                bf16x8 bf1 = u4bf(*(const uint4*)&Ws[nsub*32 + ln][(c+1)*16 + q2*8]);
                a1 = __builtin_amdgcn_mfma_f32_32x32x16_bf16(af1, bf1, a1, 0, 0, 0);
            }
            f32x16 acc = a0 + a1;
            int et = ec*2 + nsub;
            size_t base = (((size_t)(b*8 + et)) * 256 + (size_t)bx*4 + msub*2) * 64;
            repack_store(acc, q2, l, vf, base);
        }
    }
}

// ---------------------------------------------------------------------------
// Attention. 480 blocks x 512 thr, 2 blocks/CU (LDS 34.5KB, ~150 regs/wave).
// Block = (b, qh, task): slot = bid&7 -> b = slot>>1, qh = slot&1 (XCD pin:
// each XCD serves one (b,qh): K+V+Q/2 ~2.75MB L2-resident). task = bid>>3.
// Block covers 64 q-rows (q-subs 2qh, 2qh+1) x K-chunk [j0,j1).
// Wave w: S^T (ks=w&3, qg=w>>2): 4 MFMA -> 16 exp -> pack Pb[jt&1][qg][2ks..];
// PV (et=w): oa[2 qsub] += P*V, V batched in vbs[8] at iter top, kaf
// prefetched across the barrier. One barrier/iter (Pb double-buffered).
// ---------------------------------------------------------------------------
__global__ __launch_bounds__(512, 2) void attn(const uint4* __restrict__ qf,
                                               const uint4* __restrict__ kf,
                                               const uint4* __restrict__ vf,
                                               float* __restrict__ out,
                                               unsigned short* __restrict__ Op,
                                               float* __restrict__ Dp) {
    __shared__ uint4 Pb[2][2][8][64];        // 32KB, double-buffered P (64 rows)
    __shared__ float denp[4][2][64];         // [ks][qg][lane]
    __shared__ float dfin[64];

    const int bid = blockIdx.x;
    const int slot = bid & 7;
    const int b = slot >> 1, qh = slot & 1;
    const int task = bid >> 3;               // [0,60)
    int T, cc, nc;
    if (task < 12)      { T = task;                cc = 0;               nc = 1; }
    else if (task < 36) { int q = task - 12; T = 12 + (q >> 1); cc = q & 1;       nc = 2; }
    else                { int q = task - 36; T = 24 + q / 3;    cc = q - 3*(q/3); nc = 3; }
    const int n = T + 1;
    const int j0 = cc * n / nc, j1 = (cc + 1) * n / nc;

    const int tid = threadIdx.x, w = tid >> 6, l = tid & 63, ln = l & 31, q2 = l >> 5;
    const int ks = w & 3, qg = w >> 2;       // S^T role
    const int qsub = qh * 2 + qg;            // global q-sub within T-tile
    const int et = w;                        // PV role: e-tile
    const float cfac = 0.18033688011112042f; // log2(e)/sqrt(64)

    bf16x8 qv[4];
#pragma unroll
    for (int c = 0; c < 4; ++c)
        qv[c] = u4bf(qf[(((size_t)b*128 + T*4 + qsub) * 4 + c) * 64 + l]);

    f32x16 oa[2] = {};
    float den = 0.f;

    uint4 kaf[4];
#pragma unroll
    for (int c = 0; c < 4; ++c)
        kaf[c] = kf[(((size_t)b*128 + j0*4 + ks) * 4 + c) * 64 + l];

    for (int jt = j0; jt < j1; ++jt) {
        const int buf = jt & 1;
        const bool diag = (jt == T);

        // ---- batch V-chunk loads for THIS iter (latency covered below) ----
        uint4 vbs[8];
#pragma unroll
        for (int kc = 0; kc < 8; ++kc)
            vbs[kc] = vf[(((size_t)b*8 + et) * 256 + (size_t)jt*8 + kc) * 64 + l];

        // ---- S^T (one q-sub per wave) ----
        f32x16 s = {};
#pragma unroll
        for (int c = 0; c < 4; ++c)
            s = __builtin_amdgcn_mfma_f32_32x32x16_bf16(u4bf(kaf[c]), qv[c], s, 0, 0, 0);

        // ---- exp + mask + den + pack P -> LDS ----
        float pv[16], pd = 0.f;
#pragma unroll
        for (int r = 0; r < 16; ++r) {
            float e = __builtin_exp2f(s[r] * cfac);
            if (diag) {
                int klocal = 4*q2 + (r & 3) + 8*(r >> 2);
                if (ks*32 + klocal > qsub*32 + ln) e = 0.f;
            }
            pv[r] = e; pd += e;
        }
        den += pd;
#pragma unroll
        for (int quad = 0; quad < 4; ++quad) {
            unsigned int lo = pk2bf(pv[4*quad + 0], pv[4*quad + 1]);
            unsigned int hi = pk2bf(pv[4*quad + 2], pv[4*quad + 3]);
            int kcg = ks*2 + (quad >> 1);
            int h   = quad & 1;
            char* dst = (char*)&Pb[buf][qg][kcg][h*32 + ln] + q2*8;
            *(uint2*)dst = make_uint2(lo, hi);
        }
        __syncthreads();
        // ---- prefetch next K-frags (covered by PV) ----
        if (jt + 1 < j1) {
#pragma unroll
            for (int c = 0; c < 4; ++c)
                kaf[c] = kf[(((size_t)b*128 + (jt+1)*4 + ks) * 4 + c) * 64 + l];
        }
        // ---- PV: O[2 qsub][e-tile w] += P * V (V already in regs) ----
#pragma unroll
        for (int kc = 0; kc < 8; ++kc) {
            bf16x8 vb = u4bf(vbs[kc]);
#pragma unroll
            for (int qsl = 0; qsl < 2; ++qsl) {
                bf16x8 pa = u4bf(Pb[buf][qsl][kc][l]);
                oa[qsl] = __builtin_amdgcn_mfma_f32_32x32x16_bf16(pa, vb, oa[qsl], 0, 0, 0);
            }
        }
    }

    // ---- den reduction across ks-waves/halves (order matches R8 bitwise) ----
    denp[ks][qg][l] = den;
    __syncthreads();
    if (tid < 64) {
        int qgl = tid >> 5, qln = tid & 31;
        float sden = 0.f;
#pragma unroll
        for (int p = 0; p < 4; ++p)
#pragma unroll
            for (int hh = 0; hh < 2; ++hh)
                sden += denp[p][qgl][hh*32 + qln];
        dfin[tid] = (nc == 1) ? 1.0f / sden : sden;
    }
    __syncthreads();

    if (nc == 1) {
#pragma unroll
        for (int qsl = 0; qsl < 2; ++qsl)
#pragma unroll
            for (int r = 0; r < 16; ++r) {
                int qrow = qsl*32 + (r & 3) + 8*(r >> 2) + 4*q2;
                out[((size_t)b*SEQ + T*128 + qh*64 + qrow) * DM + et*32 + ln] = oa[qsl][r] * dfin[qrow];
            }
    } else if (cc == 0) {
        // chunk 0: unnormalized fp32 straight into out (combine divides later)
#pragma unroll
        for (int qsl = 0; qsl < 2; ++qsl)
#pragma unroll
            for (int r = 0; r < 16; ++r) {
                int qrow = qsl*32 + (r & 3) + 8*(r >> 2) + 4*q2;
                out[((size_t)b*SEQ + T*128 + qh*64 + qrow) * DM + et*32 + ln] = oa[qsl][r];
            }
        if (tid < 64) Dp[((size_t)b*48 + dbase(T)) * 128 + qh*64 + tid] = dfin[tid];
    } else {
        size_t pidx = (size_t)b*28 + obase(T) + (cc - 1);
#pragma unroll
        for (int qsl = 0; qsl < 2; ++qsl)
#pragma unroll
            for (int r = 0; r < 16; ++r) {
                int qrow = qsl*32 + (r & 3) + 8*(r >> 2) + 4*q2;
                Op[(pidx*128 + qh*64 + qrow) * DM + et*32 + ln] = f2bf(oa[qsl][r]);
            }
        if (tid < 64) Dp[((size_t)b*48 + dbase(T) + cc) * 128 + qh*64 + tid] = dfin[tid];
    }
}

// ---------------------------------------------------------------------------
// Combine partials for T in [12,32). grid (20, 4, 4 q-quarters) x 256 thr.
// out holds chunk-0's unnormalized fp32; add bf16 chunks >=1, divide by den.
// (Unchanged from R8.)
// ---------------------------------------------------------------------------
__global__ __launch_bounds__(256) void combine(const unsigned short* __restrict__ Op,
                                               const float* __restrict__ Dp,
                                               float* __restrict__ out) {
    const int T = 12 + blockIdx.x, b = blockIdx.y, qq = blockIdx.z;
    const int nc = (T < 24) ? 2 : 3;
    const int t = threadIdx.x;
    const size_t db = (size_t)b*48 + dbase(T);
    const size_t pb = (size_t)b*28 + obase(T);
#pragma unroll 4
    for (int r = 0; r < 32; ++r) {
        int q = qq*32 + r;
        size_t oofs = ((size_t)b*SEQ + T*128 + q) * DM + t;
        float sum = out[oofs];
        float dsum = 0.f;
        for (int c = 0; c < nc; ++c) dsum += Dp[(db + c)*128 + q];
        for (int c = 1; c < nc; ++c) {
            unsigned int uv = Op[((pb + c - 1)*128 + q) * DM + t];
            sum += __builtin_bit_cast(float, uv << 16);
        }
        out[oofs] = sum / dsum;
    }
}

// ---------------------------------------------------------------------------
extern "C" void kernel_launch(void* const* d_in, const int* in_sizes, int n_in,
                              void* d_out, int out_size, void* d_ws, size_t ws_size,
                              hipStream_t stream) {
    const float* enc_q = (const float*)d_in[0];
    const float* enc_k = (const float*)d_in[1];
    const float* enc_v = (const float*)d_in[2];
    // d_in[3] = mask (deterministic causal triu) — not needed
    const float* Wq = (const float*)d_in[4];
    const float* Wk = (const float*)d_in[5];
    const float* Wv = (const float*)d_in[6];
    float* out = (float*)d_out;

    uint4* qf = (uint4*)d_ws;                              // 2MB
    uint4* kf = qf + 131072;                               // 2MB
    uint4* vf = kf + 131072;                               // 8MB
    unsigned short* Op = (unsigned short*)(vf + 524288);   // [4][28][128][256] bf16, 7.34MB
    float* Dp = (float*)(Op + (size_t)4*28*128*256);       // [4][48][128] f32, 98KB

    proj<<<dim3(64, 4, 4), 256, 0, stream>>>(enc_q, enc_k, enc_v, Wq, Wk, Wv, qf, kf, vf);
    attn<<<480, 512, 0, stream>>>(qf, kf, vf, out, Op, Dp);
    combine<<<dim3(20, 4, 4), 256, 0, stream>>>(Op, Dp, out);
}

// Round 4
// 203.909 us; speedup vs baseline: 1.1562x; 1.0237x over previous
//
#include <hip/hip_runtime.h>

// Causal single-head attention, B=4 S=4096 Dm=256 Dqk=64, fp32 in/out.
// R12: attack the FIXED ~155us outside attn (total 208.7, attn only 51;
// total-minus-attn ~154-165us across R8/R9/R11 — 75% of runtime, unprofiled).
// Two attributable changes, attn structure FROZEN at R11 (best, 51us):
//  (a) HW bf16 conversion: f2bf/pk2bf bodies now plain (__bf16) casts ->
//      compiler emits v_cvt_pk_bf16_f32 (RNE, 1 instr/2 elems) instead of the
//      ~11-op software RNE. Same signatures, same RNE rounding -> bitwise-
//      identical outputs. Cuts ~350 VALU ops per proj stage loop and ~90 per
//      attn wave-iter (exp-pack + repack).
//  (b) proj z=2/3 merged: one z=2 block stages Xv ONCE and loops all 4
//      e-chunks -> saves 16MB of redundant HBM reads. Grid (64,4,3).
// R11 recap: Q-halved tasks, 480 blocks, 2 blocks/CU (VGPR 72, LDS 34.5KB),
// 2 independent barrier groups/CU. ws layout / task map / combine unchanged.
// ws: qf 2MB + kf 2MB + vf 8MB + Op 7.34MB + Dp 98KB = 19.5MB.

#define BATCH 4
#define SEQ   4096
#define DM    256
#define DQK   64

typedef __bf16 bf16x8 __attribute__((ext_vector_type(8)));
typedef __bf16 bf16x2 __attribute__((ext_vector_type(2)));
typedef float  f32x16 __attribute__((ext_vector_type(16)));

// HW RNE float->bf16 (v_cvt_pk_bf16_f32 via compiler). Same rounding as the
// old integer RNE -> bit-identical results, ~10x fewer VALU ops.
__device__ __forceinline__ unsigned short f2bf(float f) {
    __bf16 h = (__bf16)f;
    return __builtin_bit_cast(unsigned short, h);
}
__device__ __forceinline__ unsigned int pk2bf(float lo, float hi) {
    bf16x2 v = {(__bf16)lo, (__bf16)hi};    // elem0 low, elem1 high
    return __builtin_bit_cast(unsigned int, v);
}
__device__ __forceinline__ bf16x8 u4bf(uint4 u) { return __builtin_bit_cast(bf16x8, u); }

// Repack a 32x32x16 MFMA accumulator D[m][n] (C-layout: col(n)=lane&31,
// row(m)=(r&3)+8(r>>2)+4(lane>>5)) into two 1KB fragment chunks where the
// fragment k-dim = m and lane-dim = n, then store. (Verified R2/R3.)
__device__ __forceinline__ void repack_store(const f32x16& acc, int q2, int l,
                                             uint4* __restrict__ out, size_t tile_ofs_u4) {
    unsigned int d0[4], d1[4], p0[4], p1[4];
#pragma unroll
    for (int h = 0; h < 4; ++h) {
        d0[h] = pk2bf(acc[4*h + 0], acc[4*h + 1]);
        d1[h] = pk2bf(acc[4*h + 2], acc[4*h + 3]);
        p0[h] = __shfl_xor((int)d0[h], 32);
        p1[h] = __shfl_xor((int)d1[h], 32);
    }
#pragma unroll
    for (int kc = 0; kc < 2; ++kc) {
        int h = 2*kc + q2;
        uint4 v = (q2 == 0) ? make_uint4(d0[h], d1[h], p0[h], p1[h])
                            : make_uint4(p0[h], p1[h], d0[h], d1[h]);
        out[tile_ofs_u4 + (size_t)kc * 64 + l] = v;
    }
}

// R3 task map: nc=1 (T<12), 2 (12..23), 3 (24..31).
// Op slots (chunks cc>=1): T 12..23 -> 1 slot, 24..31 -> 2. 28/batch.
__device__ __forceinline__ int obase(int T) {
    return (T < 24) ? (T - 12) : 12 + (T - 24) * 2;
}
// Dp slots (all chunks of split tasks): 48/batch.
__device__ __forceinline__ int dbase(int T) {
    return (T < 24) ? (T - 12) * 2 : 24 + (T - 24) * 3;
}

// ---------------------------------------------------------------------------
// Fused projection. grid (64 s-tiles, 4 batch, 3): z=0 Q, z=1 K, z=2 V (all
// 4 e-chunks; Xv staged once). Coalesced fp32 staging -> bf16 LDS ->
// 32x32x16 MFMA -> frag-packed ws.
// ---------------------------------------------------------------------------
__global__ __launch_bounds__(256) void proj(const float* __restrict__ Xq,
                                            const float* __restrict__ Xk,
                                            const float* __restrict__ Xv,
                                            const float* __restrict__ Wq,
                                            const float* __restrict__ Wk,
                                            const float* __restrict__ Wv,
                                            uint4* __restrict__ qf,
                                            uint4* __restrict__ kf,
                                            uint4* __restrict__ vf) {
    __shared__ unsigned short Xs[64][264];
    __shared__ unsigned short Ws[64][264];

    const int z = blockIdx.z;
    const int bx = blockIdx.x, b = blockIdx.y;
    const float* X = (z == 0) ? Xq : (z == 1) ? Xk : Xv;
    const float* W = (z == 0) ? Wq : (z == 1) ? Wk : Wv;
    const int s0 = bx * 64;
    const int tid = threadIdx.x, w = tid >> 6, l = tid & 63, ln = l & 31, q2 = l >> 5;

#pragma unroll
    for (int i = 0; i < 16; ++i) {
        int f = i * 256 + tid;
        int r = f >> 6, c4 = f & 63;
        float4 xv = *(const float4*)&X[((size_t)b * SEQ + s0 + r) * DM + c4 * 4];
        ushort4 h; h.x = f2bf(xv.x); h.y = f2bf(xv.y); h.z = f2bf(xv.z); h.w = f2bf(xv.w);
        *(ushort4*)&Xs[r][c4 * 4] = h;
    }

    if (z < 2) {
        // ---- Q/K: D[m=e (64)][n=s (64)] ----
#pragma unroll
        for (int i = 0; i < 16; ++i) {
            int f = i * 256 + tid;
            int r = f >> 6, c4 = f & 63;
            float4 wv = *(const float4*)&W[(size_t)r * DM + c4 * 4];
            ushort4 h; h.x = f2bf(wv.x); h.y = f2bf(wv.y); h.z = f2bf(wv.z); h.w = f2bf(wv.w);
            *(ushort4*)&Ws[r][c4 * 4] = h;
        }
        __syncthreads();
        const int msub = w >> 1, nsub = w & 1;
        f32x16 a0 = {}, a1 = {};
#pragma unroll
        for (int c = 0; c < 16; c += 2) {
            bf16x8 af0 = u4bf(*(const uint4*)&Ws[msub*32 + ln][c*16 + q2*8]);
            bf16x8 bf0 = u4bf(*(const uint4*)&Xs[nsub*32 + ln][c*16 + q2*8]);
            a0 = __builtin_amdgcn_mfma_f32_32x32x16_bf16(af0, bf0, a0, 0, 0, 0);
            bf16x8 af1 = u4bf(*(const uint4*)&Ws[msub*32 + ln][(c+1)*16 + q2*8]);
            bf16x8 bf1 = u4bf(*(const uint4*)&Xs[nsub*32 + ln][(c+1)*16 + q2*8]);
            a1 = __builtin_amdgcn_mfma_f32_32x32x16_bf16(af1, bf1, a1, 0, 0, 0);
        }
        f32x16 acc = a0 + a1;
        size_t base = (((size_t)(b*128 + bx*2 + nsub)) * 4 + 2*msub) * 64;
        repack_store(acc, q2, l, (z == 0) ? qf : kf, base);
    } else {
        // ---- V: D[m=s (64)][n=e], all 4 e-chunks, Xs staged once ----
        const int msub = w & 1, nsub = w >> 1;
        for (int ec = 0; ec < 4; ++ec) {
            __syncthreads();
#pragma unroll
            for (int i = 0; i < 16; ++i) {
                int f = i * 256 + tid;
                int r = f >> 6, c4 = f & 63;
                float4 wv = *(const float4*)&W[(size_t)(ec*64 + r) * DM + c4 * 4];
                ushort4 h; h.x = f2bf(wv.x); h.y = f2bf(wv.y); h.z = f2bf(wv.z); h.w = f2bf(wv.w);
                *(ushort4*)&Ws[r][c4 * 4] = h;
            }
            __syncthreads();
            f32x16 a0 = {}, a1 = {};
#pragma unroll
            for (int c = 0; c < 16; c += 2) {
                bf16x8 af0 = u4bf(*(const uint4*)&Xs[msub*32 + ln][c*16 + q2*8]);
                bf16x8 bf0 = u4bf(*(const uint4*)&Ws[nsub*32 + ln][c*16 + q2*8]);
                a0 = __builtin_amdgcn_mfma_f32_32x32x16_bf16(af0, bf0, a0, 0, 0, 0);
                bf16x8 af1 = u4bf(*(const uint4*)&Xs[msub*32 + ln][(c+1)*16 + q2*8]);
                bf16x8 bf1 = u4bf(*(const uint4*)&Ws[nsub*32 + ln][(c+1)*16 + q2*8]);
                a1 = __builtin_amdgcn_mfma_f32_32x32x16_bf16(af1, bf1, a1, 0, 0, 0);
            }
            f32x16 acc = a0 + a1;
            int et = ec*2 + nsub;
            size_t base = (((size_t)(b*8 + et)) * 256 + (size_t)bx*4 + msub*2) * 64;
            repack_store(acc, q2, l, vf, base);
        }
    }
}

// ---------------------------------------------------------------------------
// Attention. 480 blocks x 512 thr, 2 blocks/CU (LDS 34.5KB, ~72 VGPR).
// Block = (b, qh, task): slot = bid&7 -> b = slot>>1, qh = slot&1 (XCD pin:
// each XCD serves one (b,qh): K+V+Q/2 ~2.75MB L2-resident). task = bid>>3.
// Block covers 64 q-rows (q-subs 2qh, 2qh+1) x K-chunk [j0,j1).
// Wave w: S^T (ks=w&3, qg=w>>2): 4 MFMA -> 16 exp -> pack Pb[jt&1][qg][2ks..];
// PV (et=w): oa[2 qsub] += P*V, V batched in vbs[8] at iter top, kaf
// prefetched across the barrier. One barrier/iter (Pb double-buffered).
// (Structure frozen at R11 — only pk2bf/f2bf bodies changed.)
// ---------------------------------------------------------------------------
__global__ __launch_bounds__(512, 2) void attn(const uint4* __restrict__ qf,
                                               const uint4* __restrict__ kf,
                                               const uint4* __restrict__ vf,
                                               float* __restrict__ out,
                                               unsigned short* __restrict__ Op,
                                               float* __restrict__ Dp) {
    __shared__ uint4 Pb[2][2][8][64];        // 32KB, double-buffered P (64 rows)
    __shared__ float denp[4][2][64];         // [ks][qg][lane]
    __shared__ float dfin[64];

    const int bid = blockIdx.x;
    const int slot = bid & 7;
    const int b = slot >> 1, qh = slot & 1;
    const int task = bid >> 3;               // [0,60)
    int T, cc, nc;
    if (task < 12)      { T = task;                cc = 0;               nc = 1; }
    else if (task < 36) { int q = task - 12; T = 12 + (q >> 1); cc = q & 1;       nc = 2; }
    else                { int q = task - 36; T = 24 + q / 3;    cc = q - 3*(q/3); nc = 3; }
    const int n = T + 1;
    const int j0 = cc * n / nc, j1 = (cc + 1) * n / nc;

    const int tid = threadIdx.x, w = tid >> 6, l = tid & 63, ln = l & 31, q2 = l >> 5;
    const int ks = w & 3, qg = w >> 2;       // S^T role
    const int qsub = qh * 2 + qg;            // global q-sub within T-tile
    const int et = w;                        // PV role: e-tile
    const float cfac = 0.18033688011112042f; // log2(e)/sqrt(64)

    bf16x8 qv[4];
#pragma unroll
    for (int c = 0; c < 4; ++c)
        qv[c] = u4bf(qf[(((size_t)b*128 + T*4 + qsub) * 4 + c) * 64 + l]);

    f32x16 oa[2] = {};
    float den = 0.f;

    uint4 kaf[4];
#pragma unroll
    for (int c = 0; c < 4; ++c)
        kaf[c] = kf[(((size_t)b*128 + j0*4 + ks) * 4 + c) * 64 + l];

    for (int jt = j0; jt < j1; ++jt) {
        const int buf = jt & 1;
        const bool diag = (jt == T);

        // ---- batch V-chunk loads for THIS iter (latency covered below) ----
        uint4 vbs[8];
#pragma unroll
        for (int kc = 0; kc < 8; ++kc)
            vbs[kc] = vf[(((size_t)b*8 + et) * 256 + (size_t)jt*8 + kc) * 64 + l];

        // ---- S^T (one q-sub per wave) ----
        f32x16 s = {};
#pragma unroll
        for (int c = 0; c < 4; ++c)
            s = __builtin_amdgcn_mfma_f32_32x32x16_bf16(u4bf(kaf[c]), qv[c], s, 0, 0, 0);

        // ---- exp + mask + den + pack P -> LDS ----
        float pv[16], pd = 0.f;
#pragma unroll
        for (int r = 0; r < 16; ++r) {
            float e = __builtin_exp2f(s[r] * cfac);
            if (diag) {
                int klocal = 4*q2 + (r & 3) + 8*(r >> 2);
                if (ks*32 + klocal > qsub*32 + ln) e = 0.f;
            }
            pv[r] = e; pd += e;
        }
        den += pd;
#pragma unroll
        for (int quad = 0; quad < 4; ++quad) {
            unsigned int lo = pk2bf(pv[4*quad + 0], pv[4*quad + 1]);
            unsigned int hi = pk2bf(pv[4*quad + 2], pv[4*quad + 3]);
            int kcg = ks*2 + (quad >> 1);
            int h   = quad & 1;
            char* dst = (char*)&Pb[buf][qg][kcg][h*32 + ln] + q2*8;
            *(uint2*)dst = make_uint2(lo, hi);
        }
        __syncthreads();
        // ---- prefetch next K-frags (covered by PV) ----
        if (jt + 1 < j1) {
#pragma unroll
            for (int c = 0; c < 4; ++c)
                kaf[c] = kf[(((size_t)b*128 + (jt+1)*4 + ks) * 4 + c) * 64 + l];
        }
        // ---- PV: O[2 qsub][e-tile w] += P * V (V already in regs) ----
#pragma unroll
        for (int kc = 0; kc < 8; ++kc) {
            bf16x8 vb = u4bf(vbs[kc]);
#pragma unroll
            for (int qsl = 0; qsl < 2; ++qsl) {
                bf16x8 pa = u4bf(Pb[buf][qsl][kc][l]);
                oa[qsl] = __builtin_amdgcn_mfma_f32_32x32x16_bf16(pa, vb, oa[qsl], 0, 0, 0);
            }
        }
    }

    // ---- den reduction across ks-waves/halves (order matches R8 bitwise) ----
    denp[ks][qg][l] = den;
    __syncthreads();
    if (tid < 64) {
        int qgl = tid >> 5, qln = tid & 31;
        float sden = 0.f;
#pragma unroll
        for (int p = 0; p < 4; ++p)
#pragma unroll
            for (int hh = 0; hh < 2; ++hh)
                sden += denp[p][qgl][hh*32 + qln];
        dfin[tid] = (nc == 1) ? 1.0f / sden : sden;
    }
    __syncthreads();

    if (nc == 1) {
#pragma unroll
        for (int qsl = 0; qsl < 2; ++qsl)
#pragma unroll
            for (int r = 0; r < 16; ++r) {
                int qrow = qsl*32 + (r & 3) + 8*(r >> 2) + 4*q2;
                out[((size_t)b*SEQ + T*128 + qh*64 + qrow) * DM + et*32 + ln] = oa[qsl][r] * dfin[qrow];
            }
    } else if (cc == 0) {
        // chunk 0: unnormalized fp32 straight into out (combine divides later)
#pragma unroll
        for (int qsl = 0; qsl < 2; ++qsl)
#pragma unroll
            for (int r = 0; r < 16; ++r) {
                int qrow = qsl*32 + (r & 3) + 8*(r >> 2) + 4*q2;
                out[((size_t)b*SEQ + T*128 + qh*64 + qrow) * DM + et*32 + ln] = oa[qsl][r];
            }
        if (tid < 64) Dp[((size_t)b*48 + dbase(T)) * 128 + qh*64 + tid] = dfin[tid];
    } else {
        size_t pidx = (size_t)b*28 + obase(T) + (cc - 1);
#pragma unroll
        for (int qsl = 0; qsl < 2; ++qsl)
#pragma unroll
            for (int r = 0; r < 16; ++r) {
                int qrow = qsl*32 + (r & 3) + 8*(r >> 2) + 4*q2;
                Op[(pidx*128 + qh*64 + qrow) * DM + et*32 + ln] = f2bf(oa[qsl][r]);
            }
        if (tid < 64) Dp[((size_t)b*48 + dbase(T) + cc) * 128 + qh*64 + tid] = dfin[tid];
    }
}

// ---------------------------------------------------------------------------
// Combine partials for T in [12,32). grid (20, 4, 4 q-quarters) x 256 thr.
// out holds chunk-0's unnormalized fp32; add bf16 chunks >=1, divide by den.
// (Unchanged.)
// ---------------------------------------------------------------------------
__global__ __launch_bounds__(256) void combine(const unsigned short* __restrict__ Op,
                                               const float* __restrict__ Dp,
                                               float* __restrict__ out) {
    const int T = 12 + blockIdx.x, b = blockIdx.y, qq = blockIdx.z;
    const int nc = (T < 24) ? 2 : 3;
    const int t = threadIdx.x;
    const size_t db = (size_t)b*48 + dbase(T);
    const size_t pb = (size_t)b*28 + obase(T);
#pragma unroll 4
    for (int r = 0; r < 32; ++r) {
        int q = qq*32 + r;
        size_t oofs = ((size_t)b*SEQ + T*128 + q) * DM + t;
        float sum = out[oofs];
        float dsum = 0.f;
        for (int c = 0; c < nc; ++c) dsum += Dp[(db + c)*128 + q];
        for (int c = 1; c < nc; ++c) {
            unsigned int uv = Op[((pb + c - 1)*128 + q) * DM + t];
            sum += __builtin_bit_cast(float, uv << 16);
        }
        out[oofs] = sum / dsum;
    }
}

// ---------------------------------------------------------------------------
extern "C" void kernel_launch(void* const* d_in, const int* in_sizes, int n_in,
                              void* d_out, int out_size, void* d_ws, size_t ws_size,
                              hipStream_t stream) {
    const float* enc_q = (const float*)d_in[0];
    const float* enc_k = (const float*)d_in[1];
    const float* enc_v = (const float*)d_in[2];
    // d_in[3] = mask (deterministic causal triu) — not needed
    const float* Wq = (const float*)d_in[4];
    const float* Wk = (const float*)d_in[5];
    const float* Wv = (const float*)d_in[6];
    float* out = (float*)d_out;

    uint4* qf = (uint4*)d_ws;                              // 2MB
    uint4* kf = qf + 131072;                               // 2MB
    uint4* vf = kf + 131072;                               // 8MB
    unsigned short* Op = (unsigned short*)(vf + 524288);   // [4][28][128][256] bf16, 7.34MB
    float* Dp = (float*)(Op + (size_t)4*28*128*256);       // [4][48][128] f32, 98KB

    proj<<<dim3(64, 4, 3), 256, 0, stream>>>(enc_q, enc_k, enc_v, Wq, Wk, Wv, qf, kf, vf);
    attn<<<480, 512, 0, stream>>>(qf, kf, vf, out, Op, Dp);
    combine<<<dim3(20, 4, 4), 256, 0, stream>>>(Op, Dp, out);
}